// Round 1
// baseline (4071.163 us; speedup 1.0000x reference)
//
#include <hip/hip_runtime.h>

#define EPS   1e-8f
#define LAMB  20.0f
#define NI    128
#define NR    48
#define NT    64
#define NW    100
#define ND    768

#define DC    32            // D-chunk width staged in LDS
#define STRD  33            // stage row stride (padded, odd -> conflict-free)
#define SQOFF (NW * STRD)   // 3300: offset of Q/IV rows inside stage
#define SA_ST 49            // a-tile [w][r] stride (aliases stage region)
#define ATT_ST  101         // attn  [r][w] stride
#define ATT2_ST 49          // attn2 [w][r] stride

// ws layout (floats): [0,6144) invQ, [6144,12544) invK, [12544,18688) normVi, [18688,25088) normVt

__global__ void nafs_norms(const float* __restrict__ imgQ,
                           const float* __restrict__ imgV,
                           const float* __restrict__ txtK,
                           const float* __restrict__ txtV,
                           float* __restrict__ ws) {
    int row  = blockIdx.x * 4 + (threadIdx.x >> 6);
    int lane = threadIdx.x & 63;
    const float* src;
    int inv;
    if (row < 6144)       { src = imgQ + (size_t)row * ND;           inv = 1; }
    else if (row < 12544) { src = txtK + (size_t)(row - 6144) * ND;  inv = 1; }
    else if (row < 18688) { src = imgV + (size_t)(row - 12544) * ND; inv = 0; }
    else                  { src = txtV + (size_t)(row - 18688) * ND; inv = 0; }
    float ss = 0.f;
#pragma unroll
    for (int j = 0; j < 3; ++j) {
        float4 v = *(const float4*)(src + j * 256 + lane * 4);
        ss += v.x * v.x + v.y * v.y + v.z * v.z + v.w * v.w;
    }
#pragma unroll
    for (int off = 32; off > 0; off >>= 1) ss += __shfl_down(ss, off, 64);
    if (lane == 0) {
        float n = sqrtf(ss);
        ws[row] = inv ? (1.0f / (n + EPS)) : n;
    }
}

__global__ __launch_bounds__(256, 2)
void nafs_fused(const float* __restrict__ imgQ,
                const float* __restrict__ imgV,
                const float* __restrict__ txtK,
                const float* __restrict__ txtV,
                const int*  __restrict__ tlen,
                const float* __restrict__ ws,
                float* __restrict__ out) {
    __shared__ float sStage[4900];            // staging (148x33=4884) / a-tile (100x49=4900), aliased
    __shared__ float sAttn [NR * ATT_ST];     // 48x101
    __shared__ float sAttn2[104 * ATT2_ST];   // 104x49 (rows >= L hold garbage, never used)
    __shared__ float sInvW[NW];
    __shared__ float sInv2[NR];
    __shared__ float sCos1[NR];
    __shared__ float sCos2[NW];

    const int tid = threadIdx.x;
    const int b   = blockIdx.x;
    const int t   = b >> 7;        // blocks sharing t are adjacent -> K/TV L2 reuse
    const int i   = b & 127;
    const int L   = tlen[t];
    const float Lf = (float)L;

    const float* __restrict__ invQ = ws;
    const float* __restrict__ invK = ws + 6144;
    const float* __restrict__ nVi  = ws + 12544;
    const float* __restrict__ nVt  = ws + 18688;

    const float* Kbase = txtK + (size_t)t * (NW * ND);
    const float* Qbase = imgQ + (size_t)i * (NR * ND);

    // ---------------- Phase 1: sim tile (100x48) = Kn . Qn^T -------------
    const int tw = tid >> 3;   // 0..31 (w = tw + 32*a)
    const int tr = tid & 7;    // 0..7  (r = tr*6 + c)
    float acc[4][6];
#pragma unroll
    for (int a = 0; a < 4; ++a)
#pragma unroll
        for (int c = 0; c < 6; ++c) acc[a][c] = 0.f;

    for (int dc = 0; dc < ND; dc += DC) {
        __syncthreads();
        for (int idx = tid; idx < NW * (DC / 4); idx += 256) {   // 800 float4
            int w = idx >> 3, seg = idx & 7;
            float4 v = *(const float4*)(Kbase + (size_t)w * ND + dc + seg * 4);
            float* p = &sStage[w * STRD + seg * 4];
            p[0] = v.x; p[1] = v.y; p[2] = v.z; p[3] = v.w;
        }
        for (int idx = tid; idx < NR * (DC / 4); idx += 256) {   // 384 float4
            int r = idx >> 3, seg = idx & 7;
            float4 v = *(const float4*)(Qbase + (size_t)r * ND + dc + seg * 4);
            float* p = &sStage[SQOFF + r * STRD + seg * 4];
            p[0] = v.x; p[1] = v.y; p[2] = v.z; p[3] = v.w;
        }
        __syncthreads();
#pragma unroll 4
        for (int d = 0; d < DC; ++d) {
            float kv[4], qv[6];
#pragma unroll
            for (int a = 0; a < 4; ++a) kv[a] = sStage[(tw + 32 * a) * STRD + d];  // w>=100 reads land in Q region: finite garbage, discarded
#pragma unroll
            for (int c = 0; c < 6; ++c) qv[c] = sStage[SQOFF + (tr * 6 + c) * STRD + d];
#pragma unroll
            for (int a = 0; a < 4; ++a)
#pragma unroll
                for (int c = 0; c < 6; ++c) acc[a][c] = fmaf(kv[a], qv[c], acc[a][c]);
        }
    }
    __syncthreads();
    // a = leaky_relu(sim * invK * invQ) -> sStage alias as [w][49]
#pragma unroll
    for (int a = 0; a < 4; ++a) {
        int w = tw + 32 * a;
        if (w < NW) {
            float sk = invK[t * NW + w];
#pragma unroll
            for (int c = 0; c < 6; ++c) {
                int r = tr * 6 + c;
                float s = acc[a][c] * sk * invQ[i * NR + r];
                sStage[w * SA_ST + r] = (s > 0.f) ? s : 0.1f * s;
            }
        }
    }
    __syncthreads();

    // ---------------- Phase 2: attention (both branches) -----------------
    if (tid < NW) {                       // per-w inv norm over r (branch 1)
        const float* row = &sStage[tid * SA_ST];
        float ssum = 0.f;
#pragma unroll 8
        for (int r = 0; r < NR; ++r) { float v = row[r]; ssum += v * v; }
        sInvW[tid] = 1.0f / (sqrtf(ssum) + EPS);
    } else if (tid >= 128 && tid < 128 + NR) {   // per-r inv norm over masked w (branch 2)
        int r = tid - 128;
        float ssum = 0.f;
        for (int w = 0; w < L; ++w) { float v = sStage[w * SA_ST + r]; ssum += v * v; }
        sInv2[r] = 1.0f / (sqrtf(ssum) + EPS);
    }
    __syncthreads();

    if (tid < NR) {
        // branch 1: masked softmax over w, then funcF sharpening
        const int r = tid;
        float* row = &sAttn[r * ATT_ST];
        float m = -1e30f;
        for (int w = 0; w < L; ++w) {
            float v = sStage[w * SA_ST + r] * sInvW[w] * LAMB;
            row[w] = v; m = fmaxf(m, v);
        }
        float se = 0.f;
        for (int w = 0; w < L; ++w) { float e = expf(row[w] - m); row[w] = e; se += e; }
        float isum = 1.0f / se;
        float S1 = 0.f;
        for (int w = 0; w < L; ++w) { float av = row[w] * isum; row[w] = av; S1 += av; }
        float S2 = 0.f;
        for (int w = 0; w < L; ++w) {
            float av = row[w];
            float tmp = ((av * Lf - S1) > 0.f) ? av : 0.f;
            row[w] = tmp; S2 += tmp;
        }
        float iS2 = 1.0f / ((S2 > 0.f) ? S2 : 1.0f);
        for (int w = 0; w < L; ++w) row[w] *= iS2;
        for (int w = L; w < NW; ++w) row[w] = 0.f;
    } else if (tid >= 64 && tid < 64 + NW) {
        // branch 2: softmax over r, then funcF2 sharpening (w < L only; masked w contribute 0)
        const int w = tid - 64;
        if (w < L) {
            float* row = &sAttn2[w * ATT2_ST];
            const float* arow = &sStage[w * SA_ST];
            float m = -1e30f;
#pragma unroll 8
            for (int r = 0; r < NR; ++r) {
                float v = arow[r] * sInv2[r] * LAMB;
                row[r] = v; m = fmaxf(m, v);
            }
            float se = 0.f;
            for (int r = 0; r < NR; ++r) { float e = expf(row[r] - m); row[r] = e; se += e; }
            float isum = 1.0f / se;
            float S1 = 0.f;
            for (int r = 0; r < NR; ++r) { float av = row[r] * isum; row[r] = av; S1 += av; }
            float S2 = 0.f;
            for (int r = 0; r < NR; ++r) {
                float av = row[r];
                float tmp = ((av * 48.0f - S1) > 0.f) ? av : 0.f;
                row[r] = tmp; S2 += tmp;
            }
            float iS2 = 1.0f / ((S2 > 0.f) ? S2 : 1.0f);
            for (int r = 0; r < NR; ++r) row[r] *= iS2;
        }
    }
    __syncthreads();

    // ---------------- Phase 3: fused contractions + cosine epilogue ------
    const float* TVbase = txtV + (size_t)t * (NW * ND);
    const float* IVbase = imgV + (size_t)i * (NR * ND);

    const int rt = tid >> 4;   // 0..15, r = rt*3 + j
    const int ct = tid & 15;   // 0..15, cols = ct*2 + k
    const int wt = tid >> 3;   // 0..31, w = wt*4 + j
    const int c2 = tid & 7;    // 0..7,  cols = c2*4 + k

    float ss1[3] = {0.f, 0.f, 0.f}, dd1[3] = {0.f, 0.f, 0.f};
    float ss2[4] = {0.f, 0.f, 0.f, 0.f}, dd2[4] = {0.f, 0.f, 0.f, 0.f};

    for (int dc = 0; dc < ND; dc += DC) {
        __syncthreads();
        for (int idx = tid; idx < NW * (DC / 4); idx += 256) {
            int w = idx >> 3, seg = idx & 7;
            float4 v = *(const float4*)(TVbase + (size_t)w * ND + dc + seg * 4);
            float* p = &sStage[w * STRD + seg * 4];
            p[0] = v.x; p[1] = v.y; p[2] = v.z; p[3] = v.w;
        }
        for (int idx = tid; idx < NR * (DC / 4); idx += 256) {
            int r = idx >> 3, seg = idx & 7;
            float4 v = *(const float4*)(IVbase + (size_t)r * ND + dc + seg * 4);
            float* p = &sStage[SQOFF + r * STRD + seg * 4];
            p[0] = v.x; p[1] = v.y; p[2] = v.z; p[3] = v.w;
        }
        __syncthreads();

        // branch 1: u[r-chunk] = attn[r,:] @ TV[:, cols]
        {
            float u[3][2];
#pragma unroll
            for (int j = 0; j < 3; ++j) { u[j][0] = 0.f; u[j][1] = 0.f; }
            const float* pa0 = &sAttn[(rt * 3 + 0) * ATT_ST];
            const float* pa1 = &sAttn[(rt * 3 + 1) * ATT_ST];
            const float* pa2 = &sAttn[(rt * 3 + 2) * ATT_ST];
            const float* ptv = &sStage[ct * 2];
            for (int w = 0; w < L; ++w) {
                float t0 = ptv[w * STRD], t1 = ptv[w * STRD + 1];
                float a0 = pa0[w], a1 = pa1[w], a2 = pa2[w];
                u[0][0] = fmaf(a0, t0, u[0][0]); u[0][1] = fmaf(a0, t1, u[0][1]);
                u[1][0] = fmaf(a1, t0, u[1][0]); u[1][1] = fmaf(a1, t1, u[1][1]);
                u[2][0] = fmaf(a2, t0, u[2][0]); u[2][1] = fmaf(a2, t1, u[2][1]);
            }
#pragma unroll
            for (int j = 0; j < 3; ++j) {
                int r = rt * 3 + j;
#pragma unroll
                for (int k = 0; k < 2; ++k) {
                    float uu = u[j][k];
                    ss1[j] = fmaf(uu, uu, ss1[j]);
                    dd1[j] = fmaf(uu, sStage[SQOFF + r * STRD + ct * 2 + k], dd1[j]);
                }
            }
        }
        // branch 2: u2[w-chunk] = attn2[w,:] @ IV[:, cols]   (only w < L matters)
        if (wt * 4 < L) {
            float u2[4][4];
#pragma unroll
            for (int j = 0; j < 4; ++j)
#pragma unroll
                for (int k = 0; k < 4; ++k) u2[j][k] = 0.f;
            const float* pb0 = &sAttn2[(wt * 4 + 0) * ATT2_ST];
            const float* pb1 = &sAttn2[(wt * 4 + 1) * ATT2_ST];
            const float* pb2 = &sAttn2[(wt * 4 + 2) * ATT2_ST];
            const float* pb3 = &sAttn2[(wt * 4 + 3) * ATT2_ST];
            const float* piv = &sStage[SQOFF + c2 * 4];
#pragma unroll 4
            for (int r = 0; r < NR; ++r) {
                float v0 = piv[r * STRD], v1 = piv[r * STRD + 1], v2 = piv[r * STRD + 2], v3 = piv[r * STRD + 3];
                float b0 = pb0[r], b1 = pb1[r], b2 = pb2[r], b3 = pb3[r];
                u2[0][0] = fmaf(b0, v0, u2[0][0]); u2[0][1] = fmaf(b0, v1, u2[0][1]);
                u2[0][2] = fmaf(b0, v2, u2[0][2]); u2[0][3] = fmaf(b0, v3, u2[0][3]);
                u2[1][0] = fmaf(b1, v0, u2[1][0]); u2[1][1] = fmaf(b1, v1, u2[1][1]);
                u2[1][2] = fmaf(b1, v2, u2[1][2]); u2[1][3] = fmaf(b1, v3, u2[1][3]);
                u2[2][0] = fmaf(b2, v0, u2[2][0]); u2[2][1] = fmaf(b2, v1, u2[2][1]);
                u2[2][2] = fmaf(b2, v2, u2[2][2]); u2[2][3] = fmaf(b2, v3, u2[2][3]);
                u2[3][0] = fmaf(b3, v0, u2[3][0]); u2[3][1] = fmaf(b3, v1, u2[3][1]);
                u2[3][2] = fmaf(b3, v2, u2[3][2]); u2[3][3] = fmaf(b3, v3, u2[3][3]);
            }
#pragma unroll
            for (int j = 0; j < 4; ++j) {
                int w = wt * 4 + j;
#pragma unroll
                for (int k = 0; k < 4; ++k) {
                    float uu = u2[j][k];
                    ss2[j] = fmaf(uu, uu, ss2[j]);
                    dd2[j] = fmaf(uu, sStage[w * STRD + c2 * 4 + k], dd2[j]);
                }
            }
        }
    }

    // ---------------- reductions + cosine epilogue -----------------------
#pragma unroll
    for (int j = 0; j < 3; ++j) {
        float s = ss1[j], d = dd1[j];
#pragma unroll
        for (int off = 8; off > 0; off >>= 1) {
            s += __shfl_down(s, off, 16);
            d += __shfl_down(d, off, 16);
        }
        if (ct == 0) {
            int r = rt * 3 + j;
            float nu  = sqrtf(s);
            float num = d / (nu + EPS);
            float den = fmaxf(nVi[i * NR + r] * (nu / (nu + EPS)), EPS);
            sCos1[r] = num / den;
        }
    }
#pragma unroll
    for (int j = 0; j < 4; ++j) {
        float s = ss2[j], d = dd2[j];
#pragma unroll
        for (int off = 4; off > 0; off >>= 1) {
            s += __shfl_down(s, off, 8);
            d += __shfl_down(d, off, 8);
        }
        if (c2 == 0) {
            int w = wt * 4 + j;
            if (w < L) {
                float nu  = sqrtf(s);
                float num = d / (nu + EPS);
                float den = fmaxf(nVt[t * NW + w] * (nu / (nu + EPS)), EPS);
                sCos2[w] = num / den;
            }
        }
    }
    __syncthreads();
    if (tid == 0) {
        float s = 0.f;
        for (int r = 0; r < NR; ++r) s += sCos1[r];
        out[i * NT + t] = s * (1.0f / 48.0f);            // i2t.T
    } else if (tid == 64) {
        float s = 0.f;
        for (int w = 0; w < L; ++w) s += sCos2[w];
        out[NI * NT + i * NT + t] = s / Lf;              // t2i.T
    }
}

extern "C" void kernel_launch(void* const* d_in, const int* in_sizes, int n_in,
                              void* d_out, int out_size, void* d_ws, size_t ws_size,
                              hipStream_t stream) {
    (void)in_sizes; (void)n_in; (void)out_size; (void)ws_size;
    const float* imgQ = (const float*)d_in[0];
    const float* imgV = (const float*)d_in[1];
    const float* txtK = (const float*)d_in[2];
    const float* txtV = (const float*)d_in[3];
    const int*   tlen = (const int*)d_in[4];
    float* ws  = (float*)d_ws;
    float* out = (float*)d_out;

    hipLaunchKernelGGL(nafs_norms, dim3(6272), dim3(256), 0, stream,
                       imgQ, imgV, txtK, txtV, ws);
    hipLaunchKernelGGL(nafs_fused, dim3(NT * NI), dim3(256), 0, stream,
                       imgQ, imgV, txtK, txtV, tlen, ws, out);
}

// Round 2
// 3109.893 us; speedup vs baseline: 1.3091x; 1.3091x over previous
//
#include <hip/hip_runtime.h>

#define EPS   1e-8f
#define LAMB  20.0f
#define NI    128
#define NR    48
#define NT    64
#define NW    100
#define ND    768

typedef unsigned int uint;
typedef __attribute__((ext_vector_type(8))) short short8;
typedef __attribute__((ext_vector_type(4))) float f32x4;

// ---- shA (ushort[14592], 29184 B) layout --------------------------------
// Phase 1 (aliased):  KH [112][40] @0, KL @4480, QH [48][40] @8960, QL @10880
// Phase 2/3:          attn bf16 [48][136] @0, attn2 bf16 [112][72] @6528
#define A_KH   0
#define A_KL   4480
#define A_QH   8960
#define A_QL   10880
#define A_ATT  0
#define A_ATT2 6528
#define SHA_SZ 14592
// ---- shB (float[4900], 19600 B) layout ----------------------------------
// Phase 1/2: a-tile fp32 [100][49]
// B1 chunks: IVf32 [48][33] @f0 ; TVt bf16 [32][136] @u3200
// B2 chunks: TVf32 [100][33] @f0 ; IVt bf16 [32][72] @u6656
#define B1_TVT 3200
#define B2_IVT 6656
#define SHB_SZ 4900

// ws layout (floats): [0,6144) invQ, [6144,12544) invK, [12544,18688) normVi, [18688,25088) normVt
__global__ void nafs_norms(const float* __restrict__ imgQ,
                           const float* __restrict__ imgV,
                           const float* __restrict__ txtK,
                           const float* __restrict__ txtV,
                           float* __restrict__ ws) {
    int row  = blockIdx.x * 4 + (threadIdx.x >> 6);
    int lane = threadIdx.x & 63;
    const float* src;
    int inv;
    if (row < 6144)       { src = imgQ + (size_t)row * ND;           inv = 1; }
    else if (row < 12544) { src = txtK + (size_t)(row - 6144) * ND;  inv = 1; }
    else if (row < 18688) { src = imgV + (size_t)(row - 12544) * ND; inv = 0; }
    else                  { src = txtV + (size_t)(row - 18688) * ND; inv = 0; }
    float ss = 0.f;
#pragma unroll
    for (int j = 0; j < 3; ++j) {
        float4 v = *(const float4*)(src + j * 256 + lane * 4);
        ss += v.x * v.x + v.y * v.y + v.z * v.z + v.w * v.w;
    }
#pragma unroll
    for (int off = 32; off > 0; off >>= 1) ss += __shfl_down(ss, off, 64);
    if (lane == 0) {
        float n = sqrtf(ss);
        ws[row] = inv ? (1.0f / (n + EPS)) : n;
    }
}

__device__ inline unsigned short f2bf(float f) {
    uint u = __float_as_uint(f);
    u = (u + 0x7fffu + ((u >> 16) & 1u)) >> 16;
    return (unsigned short)u;
}
__device__ inline float wredsum(float v) {
#pragma unroll
    for (int m = 1; m < 64; m <<= 1) v += __shfl_xor(v, m, 64);
    return v;
}
__device__ inline float wredmax(float v) {
#pragma unroll
    for (int m = 1; m < 64; m <<= 1) v = fmaxf(v, __shfl_xor(v, m, 64));
    return v;
}
// split-store a scaled float4 as bf16 hi + lo (ushort4 each)
__device__ inline void split_store(float4 v, unsigned short* hp, unsigned short* lp) {
    unsigned short h0 = f2bf(v.x), h1 = f2bf(v.y), h2 = f2bf(v.z), h3 = f2bf(v.w);
    float f0 = __uint_as_float((uint)h0 << 16), f1 = __uint_as_float((uint)h1 << 16);
    float f2 = __uint_as_float((uint)h2 << 16), f3 = __uint_as_float((uint)h3 << 16);
    ushort4 H; H.x = h0; H.y = h1; H.z = h2; H.w = h3;
    ushort4 L2; L2.x = f2bf(v.x - f0); L2.y = f2bf(v.y - f1); L2.z = f2bf(v.z - f2); L2.w = f2bf(v.w - f3);
    *(ushort4*)hp = H;
    *(ushort4*)lp = L2;
}

__global__ __launch_bounds__(256, 3)
void nafs_fused(const float* __restrict__ imgQ,
                const float* __restrict__ imgV,
                const float* __restrict__ txtK,
                const float* __restrict__ txtV,
                const int*  __restrict__ tlen,
                const float* __restrict__ ws,
                float* __restrict__ out) {
    __shared__ unsigned short shA[SHA_SZ];
    __shared__ float shB[SHB_SZ];
    __shared__ float sKs[NW], sQs[NR], sInvW[NW], sInv2[NR], sCos1[NR], sCos2[112];

    const int tid  = threadIdx.x;
    const int wv   = tid >> 6;
    const int lane = tid & 63;
    const int quad = lane >> 4;
    const int l15  = lane & 15;
    const int b    = blockIdx.x;
    const int t    = b >> 7;       // blocks sharing t adjacent -> K/TV L2 reuse
    const int i    = b & 127;
    const int L    = tlen[t];
    const float Lf = (float)L;

    const float* __restrict__ invQ = ws;
    const float* __restrict__ invK = ws + 6144;
    const float* __restrict__ nVi  = ws + 12544;
    const float* __restrict__ nVt  = ws + 18688;

    const float* Kbase  = txtK + (size_t)t * (NW * ND);
    const float* Qbase  = imgQ + (size_t)i * (NR * ND);
    const float* TVbase = txtV + (size_t)t * (NW * ND);
    const float* IVbase = imgV + (size_t)i * (NR * ND);

    if (tid < NW)                  sKs[tid]       = invK[t * NW + tid];
    else if (tid < NW + NR)        sQs[tid - NW]  = invQ[i * NR + (tid - NW)];

    // ================= Phase 1: sim (112x48) via bf16x3 split MFMA =======
    const int mt0 = wv * 2, mt1 = wv * 2 + 1;   // m-tiles (w): 7 tiles over 4 waves
    f32x4 acc[2][3];
#pragma unroll
    for (int a = 0; a < 2; ++a)
#pragma unroll
        for (int n = 0; n < 3; ++n) acc[a][n] = (f32x4){0.f, 0.f, 0.f, 0.f};

    for (int dc = 0; dc < ND; dc += 32) {
        __syncthreads();
        for (int idx = tid; idx < 112 * 8; idx += 256) {          // K rows (+zero pad)
            int w = idx >> 3, seg = idx & 7;
            float4 v;
            if (w < NW) {
                v = *(const float4*)(Kbase + (size_t)w * ND + dc + seg * 4);
                float s = sKs[w];
                v.x *= s; v.y *= s; v.z *= s; v.w *= s;
            } else { v.x = v.y = v.z = v.w = 0.f; }
            split_store(v, &shA[A_KH + w * 40 + seg * 4], &shA[A_KL + w * 40 + seg * 4]);
        }
        for (int idx = tid; idx < NR * 8; idx += 256) {           // Q rows
            int r = idx >> 3, seg = idx & 7;
            float4 v = *(const float4*)(Qbase + (size_t)r * ND + dc + seg * 4);
            float s = sQs[r];
            v.x *= s; v.y *= s; v.z *= s; v.w *= s;
            split_store(v, &shA[A_QH + r * 40 + seg * 4], &shA[A_QL + r * 40 + seg * 4]);
        }
        __syncthreads();
        short8 bh[3], bl[3];
#pragma unroll
        for (int n = 0; n < 3; ++n) {
            bh[n] = *(const short8*)&shA[A_QH + (n * 16 + l15) * 40 + quad * 8];
            bl[n] = *(const short8*)&shA[A_QL + (n * 16 + l15) * 40 + quad * 8];
        }
#pragma unroll
        for (int a = 0; a < 2; ++a) {
            int m = (a == 0) ? mt0 : mt1;
            if (m < 7) {
                short8 ah = *(const short8*)&shA[A_KH + (m * 16 + l15) * 40 + quad * 8];
                short8 al = *(const short8*)&shA[A_KL + (m * 16 + l15) * 40 + quad * 8];
#pragma unroll
                for (int n = 0; n < 3; ++n) {
                    acc[a][n] = __builtin_amdgcn_mfma_f32_16x16x32_bf16(ah, bh[n], acc[a][n], 0, 0, 0);
                    acc[a][n] = __builtin_amdgcn_mfma_f32_16x16x32_bf16(ah, bl[n], acc[a][n], 0, 0, 0);
                    acc[a][n] = __builtin_amdgcn_mfma_f32_16x16x32_bf16(al, bh[n], acc[a][n], 0, 0, 0);
                }
            }
        }
    }
    __syncthreads();
    // a-tile = leaky_relu(sim) -> shB [w][49]   (C layout: row=quad*4+reg, col=l15)
#pragma unroll
    for (int a = 0; a < 2; ++a) {
        int m = (a == 0) ? mt0 : mt1;
        if (m < 7) {
#pragma unroll
            for (int n = 0; n < 3; ++n) {
#pragma unroll
                for (int reg = 0; reg < 4; ++reg) {
                    int w = m * 16 + quad * 4 + reg;
                    if (w < NW) {
                        float s = acc[a][n][reg];
                        shB[w * 49 + n * 16 + l15] = (s > 0.f) ? s : 0.1f * s;
                    }
                }
            }
        }
    }
    __syncthreads();

    // ================= Phase 2: norms + both attentions ==================
    if (tid < NW) {
        float ssum = 0.f;
#pragma unroll 8
        for (int r = 0; r < NR; ++r) { float v = shB[tid * 49 + r]; ssum += v * v; }
        sInvW[tid] = 1.0f / (sqrtf(ssum) + EPS);
    } else if (tid >= 128 && tid < 128 + NR) {
        int r = tid - 128;
        float ssum = 0.f;
        for (int w = 0; w < L; ++w) { float v = shB[w * 49 + r]; ssum += v * v; }
        sInv2[r] = 1.0f / (sqrtf(ssum) + EPS);
    }
    __syncthreads();

    // branch-1 attn: wave-parallel, row r, lanes cover w and w+64
    for (int r = wv; r < NR; r += 4) {
        int w1 = lane, w2 = lane + 64;
        int v1ok = (w1 < L), v2ok = (w2 < L);
        float v1 = v1ok ? shB[w1 * 49 + r] * sInvW[w1] * LAMB : -1e30f;
        float v2 = v2ok ? shB[w2 * 49 + r] * sInvW[w2] * LAMB : -1e30f;
        float m  = wredmax(fmaxf(v1, v2));
        float e1 = v1ok ? expf(v1 - m) : 0.f;
        float e2 = v2ok ? expf(v2 - m) : 0.f;
        float inv = 1.0f / wredsum(e1 + e2);
        float p1 = e1 * inv, p2 = e2 * inv;
        float S1 = wredsum(p1 + p2);
        float t1 = ((p1 * Lf - S1) > 0.f) ? p1 : 0.f;
        float t2 = ((p2 * Lf - S1) > 0.f) ? p2 : 0.f;
        float S2 = wredsum(t1 + t2);
        float iS2 = 1.0f / ((S2 > 0.f) ? S2 : 1.0f);
        shA[A_ATT + r * 136 + w1] = f2bf(t1 * iS2);
        shA[A_ATT + r * 136 + w2] = f2bf(t2 * iS2);
    }
    // branch-2 attn2: wave-parallel, row w, lanes cover r (48 active)
    for (int w = wv; w < L; w += 4) {
        int rok = (lane < NR);
        float v = rok ? shB[w * 49 + lane] * sInv2[lane] * LAMB : -1e30f;
        float m = wredmax(v);
        float e = rok ? expf(v - m) : 0.f;
        float inv = 1.0f / wredsum(e);
        float p = e * inv;
        float S1 = wredsum(p);
        float tm = ((p * 48.0f - S1) > 0.f) ? p : 0.f;
        float S2 = wredsum(tm);
        float iS2 = 1.0f / ((S2 > 0.f) ? S2 : 1.0f);
        shA[A_ATT2 + w * 72 + lane] = f2bf(tm * iS2);   // lanes>=48 write 0
    }
    for (int w = L + wv; w < 112; w += 4) shA[A_ATT2 + w * 72 + lane] = 0;  // zero pad rows
    __syncthreads();

    // ================= Phase B1: weiText cosine ==========================
    unsigned short* shBu = (unsigned short*)shB;
    const int kk = (L + 31) >> 5;
    float ss1[4] = {0.f, 0.f, 0.f, 0.f}, dd1[4] = {0.f, 0.f, 0.f, 0.f};
    const int mt = wv;   // waves 0..2 own r-tiles; wave3 stages only
    const int cgrp = tid >> 5, ccol = tid & 31;

    for (int cc = 0; cc < ND; cc += 32) {
        __syncthreads();
        for (int w = cgrp; w < 128; w += 8) {          // TVt bf16 [32c][136w]
            float val = (w < NW) ? TVbase[(size_t)w * ND + cc + ccol] : 0.f;
            shBu[B1_TVT + ccol * 136 + w] = f2bf(val);
        }
        for (int idx = tid; idx < NR * 8; idx += 256) { // IV fp32 [48][33]
            int r = idx >> 3, seg = idx & 7;
            float4 v = *(const float4*)(IVbase + (size_t)r * ND + cc + seg * 4);
            float* p = &shB[r * 33 + seg * 4];
            p[0] = v.x; p[1] = v.y; p[2] = v.z; p[3] = v.w;
        }
        __syncthreads();
        if (mt < 3) {
            f32x4 u[2] = {(f32x4){0.f,0.f,0.f,0.f}, (f32x4){0.f,0.f,0.f,0.f}};
            for (int ks = 0; ks < kk; ++ks) {
                short8 a = *(const short8*)&shA[A_ATT + (mt * 16 + l15) * 136 + ks * 32 + quad * 8];
#pragma unroll
                for (int n = 0; n < 2; ++n) {
                    short8 bb = *(const short8*)&shBu[B1_TVT + (n * 16 + l15) * 136 + ks * 32 + quad * 8];
                    u[n] = __builtin_amdgcn_mfma_f32_16x16x32_bf16(a, bb, u[n], 0, 0, 0);
                }
            }
#pragma unroll
            for (int n = 0; n < 2; ++n) {
#pragma unroll
                for (int reg = 0; reg < 4; ++reg) {
                    int r = mt * 16 + quad * 4 + reg;
                    float uu = u[n][reg];
                    ss1[reg] = fmaf(uu, uu, ss1[reg]);
                    dd1[reg] = fmaf(uu, shB[r * 33 + n * 16 + l15], dd1[reg]);
                }
            }
        }
    }
    if (mt < 3) {
#pragma unroll
        for (int reg = 0; reg < 4; ++reg) {
            float s = ss1[reg], d = dd1[reg];
#pragma unroll
            for (int m = 1; m < 16; m <<= 1) { s += __shfl_xor(s, m, 64); d += __shfl_xor(d, m, 64); }
            if (l15 == 0) {
                int r = mt * 16 + quad * 4 + reg;
                float nu  = sqrtf(s);
                float num = d / (nu + EPS);
                float den = fmaxf(nVi[i * NR + r] * (nu / (nu + EPS)), EPS);
                sCos1[r] = num / den;
            }
        }
    }

    // ================= Phase B2: weiImage cosine =========================
    const int ntot = (L + 15) >> 4;
    float ss2[2] = {0.f, 0.f}, dd2[2] = {0.f, 0.f};

    for (int cc = 0; cc < ND; cc += 32) {
        __syncthreads();
        for (int idx = tid; idx < NW * 8; idx += 256) { // TV fp32 [100][33]
            int w = idx >> 3, seg = idx & 7;
            float4 v = *(const float4*)(TVbase + (size_t)w * ND + cc + seg * 4);
            float* p = &shB[w * 33 + seg * 4];
            p[0] = v.x; p[1] = v.y; p[2] = v.z; p[3] = v.w;
        }
        for (int r = cgrp; r < 64; r += 8) {            // IVt bf16 [32c][72r]
            float val = (r < NR) ? IVbase[(size_t)r * ND + cc + ccol] : 0.f;
            shBu[B2_IVT + ccol * 72 + r] = f2bf(val);
        }
        __syncthreads();
#pragma unroll
        for (int pp = 0; pp < 2; ++pp) {
            int nt = wv + 4 * pp;
            if (nt < ntot) {
                f32x4 u[2] = {(f32x4){0.f,0.f,0.f,0.f}, (f32x4){0.f,0.f,0.f,0.f}};
#pragma unroll
                for (int ks = 0; ks < 2; ++ks) {
                    short8 bb = *(const short8*)&shA[A_ATT2 + (nt * 16 + l15) * 72 + ks * 32 + quad * 8];
#pragma unroll
                    for (int mm = 0; mm < 2; ++mm) {
                        short8 aa = *(const short8*)&shBu[B2_IVT + (mm * 16 + l15) * 72 + ks * 32 + quad * 8];
                        u[mm] = __builtin_amdgcn_mfma_f32_16x16x32_bf16(aa, bb, u[mm], 0, 0, 0);
                    }
                }
                int w = nt * 16 + l15;
                float tvok = (w < L) ? 1.f : 0.f;
#pragma unroll
                for (int mm = 0; mm < 2; ++mm) {
#pragma unroll
                    for (int reg = 0; reg < 4; ++reg) {
                        int c = mm * 16 + quad * 4 + reg;
                        float uu = u[mm][reg];
                        float tv = (w < L) ? shB[w * 33 + c] : 0.f;
                        ss2[pp] = fmaf(uu, uu, ss2[pp]);
                        dd2[pp] = fmaf(uu, tv * tvok, dd2[pp]);
                    }
                }
            }
        }
    }
#pragma unroll
    for (int pp = 0; pp < 2; ++pp) {
        int nt = wv + 4 * pp;
        if (nt < ntot) {
            float s = ss2[pp], d = dd2[pp];
            s += __shfl_xor(s, 16, 64); d += __shfl_xor(d, 16, 64);
            s += __shfl_xor(s, 32, 64); d += __shfl_xor(d, 32, 64);
            if (quad == 0) {
                int w = nt * 16 + l15;
                if (w < L) {
                    float nu  = sqrtf(s);
                    float num = d / (nu + EPS);
                    float den = fmaxf(nVt[t * NW + w] * (nu / (nu + EPS)), EPS);
                    sCos2[w] = num / den;
                }
            }
        }
    }
    __syncthreads();
    if (tid == 0) {
        float s = 0.f;
        for (int r = 0; r < NR; ++r) s += sCos1[r];
        out[i * NT + t] = s * (1.0f / 48.0f);            // i2t.T
    } else if (tid == 64) {
        float s = 0.f;
        for (int w = 0; w < L; ++w) s += sCos2[w];
        out[NI * NT + i * NT + t] = s / Lf;              // t2i.T
    }
}

extern "C" void kernel_launch(void* const* d_in, const int* in_sizes, int n_in,
                              void* d_out, int out_size, void* d_ws, size_t ws_size,
                              hipStream_t stream) {
    (void)in_sizes; (void)n_in; (void)out_size; (void)ws_size;
    const float* imgQ = (const float*)d_in[0];
    const float* imgV = (const float*)d_in[1];
    const float* txtK = (const float*)d_in[2];
    const float* txtV = (const float*)d_in[3];
    const int*   tlen = (const int*)d_in[4];
    float* ws  = (float*)d_ws;
    float* out = (float*)d_out;

    hipLaunchKernelGGL(nafs_norms, dim3(6272), dim3(256), 0, stream,
                       imgQ, imgV, txtK, txtV, ws);
    hipLaunchKernelGGL(nafs_fused, dim3(NT * NI), dim3(256), 0, stream,
                       imgQ, imgV, txtK, txtV, tlen, ws, out);
}

// Round 3
// 1823.789 us; speedup vs baseline: 2.2323x; 1.7052x over previous
//
#include <hip/hip_runtime.h>

#define EPS   1e-8f
#define LAMB  20.0f
#define NI    128
#define NR    48
#define NT    64
#define NW    100
#define ND    768

typedef unsigned int uint;
typedef unsigned short ushortt;
typedef __attribute__((ext_vector_type(8))) short short8;
typedef __attribute__((ext_vector_type(4))) float f32x4;

// ======================= ws layout (fast path) ===========================
// floats: [0,6144) invQ, [6144,12544) invK, [12544,18688) nVi, [18688,25088) nVt
// bytes:
#define OFF_KHI  102400ULL                 // bf16 [64][128][768] (w>=100 zero)
#define OFF_KLO  12685312ULL
#define OFF_QHI  25268224ULL               // bf16 [128][48][768]
#define OFF_QLO  34705408ULL
#define OFF_TVT  44142592ULL               // bf16 [64][768][128] (w>=100 zero)
#define OFF_IVT  56725504ULL               // bf16 [128][768][64] (r>=48 zero)
#define WS_NEED  69308416ULL

__device__ inline unsigned short f2bf(float f) {
    uint u = __float_as_uint(f);
    u = (u + 0x7fffu + ((u >> 16) & 1u)) >> 16;
    return (unsigned short)u;
}
__device__ inline float bf2f(unsigned short h) {
    return __uint_as_float((uint)h << 16);
}
__device__ inline float wredsum(float v) {
#pragma unroll
    for (int m = 1; m < 64; m <<= 1) v += __shfl_xor(v, m, 64);
    return v;
}
__device__ inline float wredmax(float v) {
#pragma unroll
    for (int m = 1; m < 64; m <<= 1) v = fmaxf(v, __shfl_xor(v, m, 64));
    return v;
}
__device__ inline void split_store(float4 v, ushortt* hp, ushortt* lp) {
    unsigned short h0 = f2bf(v.x), h1 = f2bf(v.y), h2 = f2bf(v.z), h3 = f2bf(v.w);
    float f0 = bf2f(h0), f1 = bf2f(h1), f2 = bf2f(h2), f3 = bf2f(h3);
    ushort4 H; H.x = h0; H.y = h1; H.z = h2; H.w = h3;
    ushort4 L2; L2.x = f2bf(v.x - f0); L2.y = f2bf(v.y - f1); L2.z = f2bf(v.z - f2); L2.w = f2bf(v.w - f3);
    *(ushort4*)hp = H;
    *(ushort4*)lp = L2;
}

// ======================= prep kernels ====================================
__global__ void nafs_norms(const float* __restrict__ imgQ,
                           const float* __restrict__ imgV,
                           const float* __restrict__ txtK,
                           const float* __restrict__ txtV,
                           float* __restrict__ ws) {
    int row  = blockIdx.x * 4 + (threadIdx.x >> 6);
    int lane = threadIdx.x & 63;
    const float* src;
    int inv;
    if (row < 6144)       { src = imgQ + (size_t)row * ND;           inv = 1; }
    else if (row < 12544) { src = txtK + (size_t)(row - 6144) * ND;  inv = 1; }
    else if (row < 18688) { src = imgV + (size_t)(row - 12544) * ND; inv = 0; }
    else                  { src = txtV + (size_t)(row - 18688) * ND; inv = 0; }
    float ss = 0.f;
#pragma unroll
    for (int j = 0; j < 3; ++j) {
        float4 v = *(const float4*)(src + j * 256 + lane * 4);
        ss += v.x * v.x + v.y * v.y + v.z * v.z + v.w * v.w;
    }
#pragma unroll
    for (int off = 32; off > 0; off >>= 1) ss += __shfl_down(ss, off, 64);
    if (lane == 0) {
        float n = sqrtf(ss);
        ws[row] = inv ? (1.0f / (n + EPS)) : n;
    }
}

// one block per output row; K rows padded to 128/t (zeros), Q rows dense
__global__ void nafs_convert(const float* __restrict__ txtK,
                             const float* __restrict__ imgQ,
                             const float* __restrict__ ws,
                             ushortt* __restrict__ khi, ushortt* __restrict__ klo,
                             ushortt* __restrict__ qhi, ushortt* __restrict__ qlo) {
    int row = blockIdx.x;
    int c4  = threadIdx.x;
    if (c4 >= 192) return;
    if (row < 8192) {
        int t = row >> 7, w = row & 127;
        size_t o = (size_t)row * ND + c4 * 4;
        if (w < NW) {
            float s = ws[6144 + t * NW + w];
            float4 v = *(const float4*)&txtK[((size_t)t * NW + w) * ND + c4 * 4];
            v.x *= s; v.y *= s; v.z *= s; v.w *= s;
            split_store(v, &khi[o], &klo[o]);
        } else {
            ushort4 z; z.x = z.y = z.z = z.w = 0;
            *(ushort4*)&khi[o] = z; *(ushort4*)&klo[o] = z;
        }
    } else {
        int q = row - 8192;
        float s = ws[q];
        float4 v = *(const float4*)&imgQ[(size_t)q * ND + c4 * 4];
        v.x *= s; v.y *= s; v.z *= s; v.w *= s;
        size_t o = (size_t)q * ND + c4 * 4;
        split_store(v, &qhi[o], &qlo[o]);
    }
}

// TV [t][w][d] fp32 -> TVt [t][d][128] bf16  (w>=100 zero)
__global__ void nafs_ttv(const float* __restrict__ txtV, ushortt* __restrict__ tvt) {
    __shared__ float sT[128 * 33];
    int t = blockIdx.x / 24, dt = blockIdx.x % 24, d0 = dt * 32;
    int tid = threadIdx.x;
    for (int idx = tid; idx < 128 * 8; idx += 256) {
        int w = idx >> 3, c4 = idx & 7;
        float4 v;
        if (w < NW) v = *(const float4*)&txtV[((size_t)t * NW + w) * ND + d0 + c4 * 4];
        else { v.x = v.y = v.z = v.w = 0.f; }
        float* p = &sT[w * 33 + c4 * 4];
        p[0] = v.x; p[1] = v.y; p[2] = v.z; p[3] = v.w;
    }
    __syncthreads();
    for (int idx = tid; idx < 32 * 32; idx += 256) {
        int w4 = idx & 31, c = idx >> 5;
        ushort4 o;
        o.x = f2bf(sT[(w4 * 4 + 0) * 33 + c]);
        o.y = f2bf(sT[(w4 * 4 + 1) * 33 + c]);
        o.z = f2bf(sT[(w4 * 4 + 2) * 33 + c]);
        o.w = f2bf(sT[(w4 * 4 + 3) * 33 + c]);
        *(ushort4*)&tvt[((size_t)t * ND + d0 + c) * 128 + w4 * 4] = o;
    }
}

// IV [i][r][d] fp32 -> IVt [i][d][64] bf16 (r>=48 zero)
__global__ void nafs_tiv(const float* __restrict__ imgV, ushortt* __restrict__ ivt) {
    __shared__ float sT[64 * 33];
    int i = blockIdx.x / 24, dt = blockIdx.x % 24, d0 = dt * 32;
    int tid = threadIdx.x;
    for (int idx = tid; idx < 64 * 8; idx += 256) {
        int r = idx >> 3, c4 = idx & 7;
        float4 v;
        if (r < NR) v = *(const float4*)&imgV[((size_t)i * NR + r) * ND + d0 + c4 * 4];
        else { v.x = v.y = v.z = v.w = 0.f; }
        float* p = &sT[r * 33 + c4 * 4];
        p[0] = v.x; p[1] = v.y; p[2] = v.z; p[3] = v.w;
    }
    __syncthreads();
    for (int idx = tid; idx < 16 * 32; idx += 256) {
        int r4 = idx & 15, c = idx >> 4;
        ushort4 o;
        o.x = f2bf(sT[(r4 * 4 + 0) * 33 + c]);
        o.y = f2bf(sT[(r4 * 4 + 1) * 33 + c]);
        o.z = f2bf(sT[(r4 * 4 + 2) * 33 + c]);
        o.w = f2bf(sT[(r4 * 4 + 3) * 33 + c]);
        *(ushort4*)&ivt[((size_t)i * ND + d0 + c) * 64 + r4 * 4] = o;
    }
}

// ======================= fused kernel (fast path) ========================
__global__ __launch_bounds__(256, 3)
void nafs_fused2(const float* __restrict__ imgV,
                 const int*  __restrict__ tlen,
                 const float* __restrict__ ws,
                 const ushortt* __restrict__ khi, const ushortt* __restrict__ klo,
                 const ushortt* __restrict__ qhi, const ushortt* __restrict__ qlo,
                 const ushortt* __restrict__ tvt, const ushortt* __restrict__ ivt,
                 float* __restrict__ out) {
    __shared__ float   aT[112 * 49];          // leaky(sim) fp32, odd stride
    __shared__ ushortt shATT[48 * 128];       // attn bf16, XOR-swizzled blocks
    __shared__ ushortt shATT2[112 * 64];      // attn2 bf16, XOR-swizzled blocks
    __shared__ float sInvW[NW], sInv2[NR], sCos1[NR], sCos2[112], sSS2[112], sDD2[112];

    const int tid  = threadIdx.x;
    const int wv   = tid >> 6;
    const int lane = tid & 63;
    const int quad = lane >> 4;
    const int l15  = lane & 15;
    const int key  = l15 & 7;
    const int b    = blockIdx.x;
    const int t    = b >> 7;
    const int i    = b & 127;
    const int L    = tlen[t];
    const float Lf = (float)L;

    const float* __restrict__ nVi = ws + 12544;
    const float* __restrict__ nVt = ws + 18688;

    if (tid < 112) { sSS2[tid] = 0.f; sDD2[tid] = 0.f; }

    // ---------------- Phase 1: sim via 3-pass split bf16 MFMA ------------
    // 8 m-tiles (K padded to 112..128 zero rows): wave owns m0=wv, m1=wv+4
    const int m0 = wv, m1 = wv + 4;
    const ushortt* pK0h = khi + ((size_t)t * 128 + m0 * 16 + l15) * ND + quad * 8;
    const ushortt* pK0l = klo + ((size_t)t * 128 + m0 * 16 + l15) * ND + quad * 8;
    const ushortt* pK1h = khi + ((size_t)t * 128 + m1 * 16 + l15) * ND + quad * 8;
    const ushortt* pK1l = klo + ((size_t)t * 128 + m1 * 16 + l15) * ND + quad * 8;
    const ushortt* pQh  = qhi + ((size_t)i * NR + l15) * ND + quad * 8;   // + n*16*ND
    const ushortt* pQl  = qlo + ((size_t)i * NR + l15) * ND + quad * 8;

    f32x4 acc[2][3];
#pragma unroll
    for (int a = 0; a < 2; ++a)
#pragma unroll
        for (int n = 0; n < 3; ++n) acc[a][n] = (f32x4){0.f, 0.f, 0.f, 0.f};

    short8 cA0h, cA0l, cA1h, cA1l, cB0h, cB0l, cB1h, cB1l, cB2h, cB2l;
    cA0h = *(const short8*)(pK0h); cA0l = *(const short8*)(pK0l);
    cA1h = *(const short8*)(pK1h); cA1l = *(const short8*)(pK1l);
    cB0h = *(const short8*)(pQh);            cB0l = *(const short8*)(pQl);
    cB1h = *(const short8*)(pQh + 16 * ND);  cB1l = *(const short8*)(pQl + 16 * ND);
    cB2h = *(const short8*)(pQh + 32 * ND);  cB2l = *(const short8*)(pQl + 32 * ND);

    for (int dc = 0; dc < ND; dc += 32) {
        short8 nA0h, nA0l, nA1h, nA1l, nB0h, nB0l, nB1h, nB1l, nB2h, nB2l;
        int dn = dc + 32;
        if (dn < ND) {
            nA0h = *(const short8*)(pK0h + dn); nA0l = *(const short8*)(pK0l + dn);
            nA1h = *(const short8*)(pK1h + dn); nA1l = *(const short8*)(pK1l + dn);
            nB0h = *(const short8*)(pQh + dn);           nB0l = *(const short8*)(pQl + dn);
            nB1h = *(const short8*)(pQh + 16 * ND + dn); nB1l = *(const short8*)(pQl + 16 * ND + dn);
            nB2h = *(const short8*)(pQh + 32 * ND + dn); nB2l = *(const short8*)(pQl + 32 * ND + dn);
        }
        acc[0][0] = __builtin_amdgcn_mfma_f32_16x16x32_bf16(cA0h, cB0h, acc[0][0], 0, 0, 0);
        acc[0][0] = __builtin_amdgcn_mfma_f32_16x16x32_bf16(cA0h, cB0l, acc[0][0], 0, 0, 0);
        acc[0][0] = __builtin_amdgcn_mfma_f32_16x16x32_bf16(cA0l, cB0h, acc[0][0], 0, 0, 0);
        acc[0][1] = __builtin_amdgcn_mfma_f32_16x16x32_bf16(cA0h, cB1h, acc[0][1], 0, 0, 0);
        acc[0][1] = __builtin_amdgcn_mfma_f32_16x16x32_bf16(cA0h, cB1l, acc[0][1], 0, 0, 0);
        acc[0][1] = __builtin_amdgcn_mfma_f32_16x16x32_bf16(cA0l, cB1h, acc[0][1], 0, 0, 0);
        acc[0][2] = __builtin_amdgcn_mfma_f32_16x16x32_bf16(cA0h, cB2h, acc[0][2], 0, 0, 0);
        acc[0][2] = __builtin_amdgcn_mfma_f32_16x16x32_bf16(cA0h, cB2l, acc[0][2], 0, 0, 0);
        acc[0][2] = __builtin_amdgcn_mfma_f32_16x16x32_bf16(cA0l, cB2h, acc[0][2], 0, 0, 0);
        acc[1][0] = __builtin_amdgcn_mfma_f32_16x16x32_bf16(cA1h, cB0h, acc[1][0], 0, 0, 0);
        acc[1][0] = __builtin_amdgcn_mfma_f32_16x16x32_bf16(cA1h, cB0l, acc[1][0], 0, 0, 0);
        acc[1][0] = __builtin_amdgcn_mfma_f32_16x16x32_bf16(cA1l, cB0h, acc[1][0], 0, 0, 0);
        acc[1][1] = __builtin_amdgcn_mfma_f32_16x16x32_bf16(cA1h, cB1h, acc[1][1], 0, 0, 0);
        acc[1][1] = __builtin_amdgcn_mfma_f32_16x16x32_bf16(cA1h, cB1l, acc[1][1], 0, 0, 0);
        acc[1][1] = __builtin_amdgcn_mfma_f32_16x16x32_bf16(cA1l, cB1h, acc[1][1], 0, 0, 0);
        acc[1][2] = __builtin_amdgcn_mfma_f32_16x16x32_bf16(cA1h, cB2h, acc[1][2], 0, 0, 0);
        acc[1][2] = __builtin_amdgcn_mfma_f32_16x16x32_bf16(cA1h, cB2l, acc[1][2], 0, 0, 0);
        acc[1][2] = __builtin_amdgcn_mfma_f32_16x16x32_bf16(cA1l, cB2h, acc[1][2], 0, 0, 0);
        if (dn < ND) {
            cA0h = nA0h; cA0l = nA0l; cA1h = nA1h; cA1l = nA1l;
            cB0h = nB0h; cB0l = nB0l; cB1h = nB1h; cB1l = nB1l; cB2h = nB2h; cB2l = nB2l;
        }
    }
    // write a-tile (skip zero tile m=7); C layout: row=quad*4+reg, col=l15
#pragma unroll
    for (int a = 0; a < 2; ++a) {
        int m = (a == 0) ? m0 : m1;
        if (m < 7) {
#pragma unroll
            for (int n = 0; n < 3; ++n) {
#pragma unroll
                for (int reg = 0; reg < 4; ++reg) {
                    float s = acc[a][n][reg];
                    aT[(m * 16 + quad * 4 + reg) * 49 + n * 16 + l15] = (s > 0.f) ? s : 0.1f * s;
                }
            }
        }
    }
    __syncthreads();

    // ---------------- Phase 2: norms + both attentions -------------------
    if (tid < NW) {
        float ssum = 0.f;
#pragma unroll 8
        for (int r = 0; r < NR; ++r) { float v = aT[tid * 49 + r]; ssum += v * v; }
        sInvW[tid] = 1.0f / (sqrtf(ssum) + EPS);
    } else if (tid >= 128 && tid < 128 + NR) {
        int r = tid - 128;
        float ssum = 0.f;
        for (int w = 0; w < L; ++w) { float v = aT[w * 49 + r]; ssum += v * v; }
        sInv2[r] = 1.0f / (sqrtf(ssum) + EPS);
    }
    __syncthreads();

    for (int r = wv; r < NR; r += 4) {
        int w1 = lane, w2 = lane + 64;
        int v1ok = (w1 < L), v2ok = (w2 < L);
        float v1 = v1ok ? aT[w1 * 49 + r] * sInvW[w1] * LAMB : -1e30f;
        float v2 = v2ok ? aT[w2 * 49 + r] * sInvW[w2] * LAMB : -1e30f;
        float m  = wredmax(fmaxf(v1, v2));
        float e1 = v1ok ? expf(v1 - m) : 0.f;
        float e2 = v2ok ? expf(v2 - m) : 0.f;
        float inv = 1.0f / wredsum(e1 + e2);
        float p1 = e1 * inv, p2 = e2 * inv;
        float S1 = wredsum(p1 + p2);
        float t1 = ((p1 * Lf - S1) > 0.f) ? p1 : 0.f;
        float t2 = ((p2 * Lf - S1) > 0.f) ? p2 : 0.f;
        float S2 = wredsum(t1 + t2);
        float iS2 = 1.0f / ((S2 > 0.f) ? S2 : 1.0f);
        shATT[r * 128 + (((w1 >> 3) ^ (r & 7)) << 3) + (w1 & 7)] = f2bf(t1 * iS2);
        shATT[r * 128 + (((w2 >> 3) ^ (r & 7)) << 3) + (w2 & 7)] = f2bf(t2 * iS2);
    }
    for (int w = wv; w < L; w += 4) {
        int rok = (lane < NR);
        float v = rok ? aT[w * 49 + lane] * sInv2[lane] * LAMB : -1e30f;
        float m = wredmax(v);
        float e = rok ? expf(v - m) : 0.f;
        float inv = 1.0f / wredsum(e);
        float p = e * inv;
        float S1 = wredsum(p);
        float tm = ((p * 48.0f - S1) > 0.f) ? p : 0.f;
        float S2 = wredsum(tm);
        float iS2 = 1.0f / ((S2 > 0.f) ? S2 : 1.0f);
        shATT2[w * 64 + (((lane >> 3) ^ (w & 7)) << 3) + (lane & 7)] = f2bf(tm * iS2);
    }
    for (int w = L + wv; w < 112; w += 4) shATT2[w * 64 + lane] = 0;
    __syncthreads();

    // ---------------- B1: weiText cosine (waves 0-2, barrier-free) -------
    const int kk   = (L + 31) >> 5;
    const int ntot = (L + 15) >> 4;
    if (wv < 3) {
        float ss1[4] = {0.f, 0.f, 0.f, 0.f}, dd1[4] = {0.f, 0.f, 0.f, 0.f};
        const ushortt* attRow = &shATT[(wv * 16 + l15) * 128];
        short8 af[4];
        for (int cc = 0; cc < 24; ++cc) {
#pragma unroll
            for (int ks = 0; ks < 4; ++ks)
                if (ks < kk) af[ks] = *(const short8*)&attRow[(((ks * 4 + quad) ^ key)) << 3];
#pragma unroll
            for (int n = 0; n < 2; ++n) {
                f32x4 u = (f32x4){0.f, 0.f, 0.f, 0.f};
                const ushortt* tvc = &tvt[((size_t)t * ND + cc * 32 + n * 16 + l15) * 128 + quad * 8];
#pragma unroll
                for (int ks = 0; ks < 4; ++ks)
                    if (ks < kk) {
                        short8 bb = *(const short8*)&tvc[ks * 32];
                        u = __builtin_amdgcn_mfma_f32_16x16x32_bf16(af[ks], bb, u, 0, 0, 0);
                    }
                const float* ivp = &imgV[((size_t)i * NR + wv * 16 + quad * 4) * ND + cc * 32 + n * 16 + l15];
#pragma unroll
                for (int reg = 0; reg < 4; ++reg) {
                    float uu = u[reg];
                    ss1[reg] = fmaf(uu, uu, ss1[reg]);
                    dd1[reg] = fmaf(uu, ivp[reg * ND], dd1[reg]);
                }
            }
        }
#pragma unroll
        for (int reg = 0; reg < 4; ++reg) {
            float s = ss1[reg], d = dd1[reg];
#pragma unroll
            for (int m = 1; m < 16; m <<= 1) { s += __shfl_xor(s, m, 64); d += __shfl_xor(d, m, 64); }
            if (l15 == 0) {
                int r = wv * 16 + quad * 4 + reg;
                float nu  = sqrtf(s);
                float num = d / (nu + EPS);
                float den = fmaxf(nVi[i * NR + r] * (nu / (nu + EPS)), EPS);
                sCos1[r] = num / den;
            }
        }
    }

    // ---------------- B2: weiImage cosine (all waves, barrier-free) ------
    {
        const int ctb = (wv < 3) ? wv * 10 : 30;
        const int ctn = (wv < 3) ? 10 : 18;
        const ushortt* ivtB = &ivt[(size_t)i * ND * 64];
        for (int nt = 0; nt < ntot; ++nt) {
            const ushortt* a2row = &shATT2[(nt * 16 + l15) * 64];
            short8 b0 = *(const short8*)&a2row[((quad ^ key)) << 3];
            short8 b1 = *(const short8*)&a2row[(((4 + quad) ^ key)) << 3];
            float ss = 0.f, dd = 0.f;
            for (int j = 0; j < ctn; ++j) {
                int ct = ctb + j;
                const ushortt* ap = &ivtB[(size_t)(ct * 16 + l15) * 64 + quad * 8];
                short8 a0 = *(const short8*)&ap[0];
                short8 a1 = *(const short8*)&ap[32];
                f32x4 u = (f32x4){0.f, 0.f, 0.f, 0.f};
                u = __builtin_amdgcn_mfma_f32_16x16x32_bf16(a0, b0, u, 0, 0, 0);
                u = __builtin_amdgcn_mfma_f32_16x16x32_bf16(a1, b1, u, 0, 0, 0);
                const ushortt* tvp = &tvt[((size_t)t * ND + ct * 16 + quad * 4) * 128 + nt * 16 + l15];
#pragma unroll
                for (int reg = 0; reg < 4; ++reg) {
                    float uu = u[reg];
                    ss = fmaf(uu, uu, ss);
                    dd = fmaf(uu, bf2f(tvp[reg * 128]), dd);
                }
            }
            ss += __shfl_xor(ss, 16, 64); dd += __shfl_xor(dd, 16, 64);
            ss += __shfl_xor(ss, 32, 64); dd += __shfl_xor(dd, 32, 64);
            if (quad == 0) {
                atomicAdd(&sSS2[nt * 16 + l15], ss);
                atomicAdd(&sDD2[nt * 16 + l15], dd);
            }
        }
    }
    __syncthreads();
    if (tid < 112 && tid < L) {
        float s = sSS2[tid], d = sDD2[tid];
        float nu  = sqrtf(s);
        float num = d / (nu + EPS);
        float den = fmaxf(nVt[t * NW + tid] * (nu / (nu + EPS)), EPS);
        sCos2[tid] = num / den;
    }
    __syncthreads();
    if (tid == 0) {
        float s = 0.f;
        for (int r = 0; r < NR; ++r) s += sCos1[r];
        out[i * NT + t] = s * (1.0f / 48.0f);
    } else if (tid == 64) {
        float s = 0.f;
        for (int w = 0; w < L; ++w) s += sCos2[w];
        out[NI * NT + i * NT + t] = s / Lf;
    }
}

// ======================= fallback (round-2 kernel) =======================
#define A_KH   0
#define A_KL   4480
#define A_QH   8960
#define A_QL   10880
#define A_ATT  0
#define A_ATT2 6528
#define SHA_SZ 14592
#define B1_TVT 3200
#define B2_IVT 6656
#define SHB_SZ 4900

__global__ __launch_bounds__(256, 3)
void nafs_fused_fb(const float* __restrict__ imgQ,
                   const float* __restrict__ imgV,
                   const float* __restrict__ txtK,
                   const float* __restrict__ txtV,
                   const int*  __restrict__ tlen,
                   const float* __restrict__ ws,
                   float* __restrict__ out) {
    __shared__ ushortt shA[SHA_SZ];
    __shared__ float shB[SHB_SZ];
    __shared__ float sKs[NW], sQs[NR], sInvW[NW], sInv2[NR], sCos1[NR], sCos2[112];

    const int tid  = threadIdx.x;
    const int wv   = tid >> 6;
    const int lane = tid & 63;
    const int quad = lane >> 4;
    const int l15  = lane & 15;
    const int b    = blockIdx.x;
    const int t    = b >> 7;
    const int i    = b & 127;
    const int L    = tlen[t];
    const float Lf = (float)L;

    const float* __restrict__ invQ = ws;
    const float* __restrict__ invK = ws + 6144;
    const float* __restrict__ nVi  = ws + 12544;
    const float* __restrict__ nVt  = ws + 18688;

    const float* Kbase  = txtK + (size_t)t * (NW * ND);
    const float* Qbase  = imgQ + (size_t)i * (NR * ND);
    const float* TVbase = txtV + (size_t)t * (NW * ND);
    const float* IVbase = imgV + (size_t)i * (NR * ND);

    if (tid < NW)                  sKs[tid]       = invK[t * NW + tid];
    else if (tid < NW + NR)        sQs[tid - NW]  = invQ[i * NR + (tid - NW)];

    const int mt0 = wv * 2, mt1 = wv * 2 + 1;
    f32x4 acc[2][3];
#pragma unroll
    for (int a = 0; a < 2; ++a)
#pragma unroll
        for (int n = 0; n < 3; ++n) acc[a][n] = (f32x4){0.f, 0.f, 0.f, 0.f};

    for (int dc = 0; dc < ND; dc += 32) {
        __syncthreads();
        for (int idx = tid; idx < 112 * 8; idx += 256) {
            int w = idx >> 3, seg = idx & 7;
            float4 v;
            if (w < NW) {
                v = *(const float4*)(Kbase + (size_t)w * ND + dc + seg * 4);
                float s = sKs[w];
                v.x *= s; v.y *= s; v.z *= s; v.w *= s;
            } else { v.x = v.y = v.z = v.w = 0.f; }
            split_store(v, &shA[A_KH + w * 40 + seg * 4], &shA[A_KL + w * 40 + seg * 4]);
        }
        for (int idx = tid; idx < NR * 8; idx += 256) {
            int r = idx >> 3, seg = idx & 7;
            float4 v = *(const float4*)(Qbase + (size_t)r * ND + dc + seg * 4);
            float s = sQs[r];
            v.x *= s; v.y *= s; v.z *= s; v.w *= s;
            split_store(v, &shA[A_QH + r * 40 + seg * 4], &shA[A_QL + r * 40 + seg * 4]);
        }
        __syncthreads();
        short8 bh[3], bl[3];
#pragma unroll
        for (int n = 0; n < 3; ++n) {
            bh[n] = *(const short8*)&shA[A_QH + (n * 16 + l15) * 40 + quad * 8];
            bl[n] = *(const short8*)&shA[A_QL + (n * 16 + l15) * 40 + quad * 8];
        }
#pragma unroll
        for (int a = 0; a < 2; ++a) {
            int m = (a == 0) ? mt0 : mt1;
            if (m < 7) {
                short8 ah = *(const short8*)&shA[A_KH + (m * 16 + l15) * 40 + quad * 8];
                short8 al = *(const short8*)&shA[A_KL + (m * 16 + l15) * 40 + quad * 8];
#pragma unroll
                for (int n = 0; n < 3; ++n) {
                    acc[a][n] = __builtin_amdgcn_mfma_f32_16x16x32_bf16(ah, bh[n], acc[a][n], 0, 0, 0);
                    acc[a][n] = __builtin_amdgcn_mfma_f32_16x16x32_bf16(ah, bl[n], acc[a][n], 0, 0, 0);
                    acc[a][n] = __builtin_amdgcn_mfma_f32_16x16x32_bf16(al, bh[n], acc[a][n], 0, 0, 0);
                }
            }
        }
    }
    __syncthreads();
#pragma unroll
    for (int a = 0; a < 2; ++a) {
        int m = (a == 0) ? mt0 : mt1;
        if (m < 7) {
#pragma unroll
            for (int n = 0; n < 3; ++n) {
#pragma unroll
                for (int reg = 0; reg < 4; ++reg) {
                    int w = m * 16 + quad * 4 + reg;
                    if (w < NW) {
                        float s = acc[a][n][reg];
                        shB[w * 49 + n * 16 + l15] = (s > 0.f) ? s : 0.1f * s;
                    }
                }
            }
        }
    }
    __syncthreads();

    if (tid < NW) {
        float ssum = 0.f;
#pragma unroll 8
        for (int r = 0; r < NR; ++r) { float v = shB[tid * 49 + r]; ssum += v * v; }
        sInvW[tid] = 1.0f / (sqrtf(ssum) + EPS);
    } else if (tid >= 128 && tid < 128 + NR) {
        int r = tid - 128;
        float ssum = 0.f;
        for (int w = 0; w < L; ++w) { float v = shB[w * 49 + r]; ssum += v * v; }
        sInv2[r] = 1.0f / (sqrtf(ssum) + EPS);
    }
    __syncthreads();

    for (int r = wv; r < NR; r += 4) {
        int w1 = lane, w2 = lane + 64;
        int v1ok = (w1 < L), v2ok = (w2 < L);
        float v1 = v1ok ? shB[w1 * 49 + r] * sInvW[w1] * LAMB : -1e30f;
        float v2 = v2ok ? shB[w2 * 49 + r] * sInvW[w2] * LAMB : -1e30f;
        float m  = wredmax(fmaxf(v1, v2));
        float e1 = v1ok ? expf(v1 - m) : 0.f;
        float e2 = v2ok ? expf(v2 - m) : 0.f;
        float inv = 1.0f / wredsum(e1 + e2);
        float p1 = e1 * inv, p2 = e2 * inv;
        float S1 = wredsum(p1 + p2);
        float t1 = ((p1 * Lf - S1) > 0.f) ? p1 : 0.f;
        float t2 = ((p2 * Lf - S1) > 0.f) ? p2 : 0.f;
        float S2 = wredsum(t1 + t2);
        float iS2 = 1.0f / ((S2 > 0.f) ? S2 : 1.0f);
        shA[A_ATT + r * 136 + w1] = f2bf(t1 * iS2);
        shA[A_ATT + r * 136 + w2] = f2bf(t2 * iS2);
    }
    for (int w = wv; w < L; w += 4) {
        int rok = (lane < NR);
        float v = rok ? shB[w * 49 + lane] * sInv2[lane] * LAMB : -1e30f;
        float m = wredmax(v);
        float e = rok ? expf(v - m) : 0.f;
        float inv = 1.0f / wredsum(e);
        float p = e * inv;
        float S1 = wredsum(p);
        float tm = ((p * 48.0f - S1) > 0.f) ? p : 0.f;
        float S2 = wredsum(tm);
        float iS2 = 1.0f / ((S2 > 0.f) ? S2 : 1.0f);
        shA[A_ATT2 + w * 72 + lane] = f2bf(tm * iS2);
    }
    for (int w = L + wv; w < 112; w += 4) shA[A_ATT2 + w * 72 + lane] = 0;
    __syncthreads();

    ushortt* shBu = (ushortt*)shB;
    const int kk = (L + 31) >> 5;
    float ss1[4] = {0.f, 0.f, 0.f, 0.f}, dd1[4] = {0.f, 0.f, 0.f, 0.f};
    const int mt = wv;
    const int cgrp = tid >> 5, ccol = tid & 31;

    for (int cc = 0; cc < ND; cc += 32) {
        __syncthreads();
        for (int w = cgrp; w < 128; w += 8) {
            float val = (w < NW) ? TVbase[(size_t)w * ND + cc + ccol] : 0.f;
            shBu[B1_TVT + ccol * 136 + w] = f2bf(val);
        }
        for (int idx = tid; idx < NR * 8; idx += 256) {
            int r = idx >> 3, seg = idx & 7;
            float4 v = *(const float4*)(IVbase + (size_t)r * ND + cc + seg * 4);
            float* p = &shB[r * 33 + seg * 4];
            p[0] = v.x; p[1] = v.y; p[2] = v.z; p[3] = v.w;
        }
        __syncthreads();
        if (mt < 3) {
            f32x4 u[2] = {(f32x4){0.f,0.f,0.f,0.f}, (f32x4){0.f,0.f,0.f,0.f}};
            for (int ks = 0; ks < kk; ++ks) {
                short8 a = *(const short8*)&shA[A_ATT + (mt * 16 + l15) * 136 + ks * 32 + quad * 8];
#pragma unroll
                for (int n = 0; n < 2; ++n) {
                    short8 bb = *(const short8*)&shBu[B1_TVT + (n * 16 + l15) * 136 + ks * 32 + quad * 8];
                    u[n] = __builtin_amdgcn_mfma_f32_16x16x32_bf16(a, bb, u[n], 0, 0, 0);
                }
            }
#pragma unroll
            for (int n = 0; n < 2; ++n) {
#pragma unroll
                for (int reg = 0; reg < 4; ++reg) {
                    int r = mt * 16 + quad * 4 + reg;
                    float uu = u[n][reg];
                    ss1[reg] = fmaf(uu, uu, ss1[reg]);
                    dd1[reg] = fmaf(uu, shB[r * 33 + n * 16 + l15], dd1[reg]);
                }
            }
        }
    }
    if (mt < 3) {
#pragma unroll
        for (int reg = 0; reg < 4; ++reg) {
            float s = ss1[reg], d = dd1[reg];
#pragma unroll
            for (int m = 1; m < 16; m <<= 1) { s += __shfl_xor(s, m, 64); d += __shfl_xor(d, m, 64); }
            if (l15 == 0) {
                int r = mt * 16 + quad * 4 + reg;
                float nu  = sqrtf(s);
                float num = d / (nu + EPS);
                float den = fmaxf(nVi[i * NR + r] * (nu / (nu + EPS)), EPS);
                sCos1[r] = num / den;
            }
        }
    }

    const int ntot = (L + 15) >> 4;
    float ss2[2] = {0.f, 0.f}, dd2[2] = {0.f, 0.f};

    for (int cc = 0; cc < ND; cc += 32) {
        __syncthreads();
        for (int idx = tid; idx < NW * 8; idx += 256) {
            int w = idx >> 3, seg = idx & 7;
            float4 v = *(const float4*)(TVbase + (size_t)w * ND + cc + seg * 4);
            float* p = &shB[w * 33 + seg * 4];
            p[0] = v.x; p[1] = v.y; p[2] = v.z; p[3] = v.w;
        }
        for (int r = cgrp; r < 64; r += 8) {
            float val = (r < NR) ? IVbase[(size_t)r * ND + cc + ccol] : 0.f;
            shBu[B2_IVT + ccol * 72 + r] = f2bf(val);
        }
        __syncthreads();
#pragma unroll
        for (int pp = 0; pp < 2; ++pp) {
            int nt = wv + 4 * pp;
            if (nt < ntot) {
                f32x4 u[2] = {(f32x4){0.f,0.f,0.f,0.f}, (f32x4){0.f,0.f,0.f,0.f}};
#pragma unroll
                for (int ks = 0; ks < 2; ++ks) {
                    short8 bb = *(const short8*)&shA[A_ATT2 + (nt * 16 + l15) * 72 + ks * 32 + quad * 8];
#pragma unroll
                    for (int mm = 0; mm < 2; ++mm) {
                        short8 aa = *(const short8*)&shBu[B2_IVT + (mm * 16 + l15) * 72 + ks * 32 + quad * 8];
                        u[mm] = __builtin_amdgcn_mfma_f32_16x16x32_bf16(aa, bb, u[mm], 0, 0, 0);
                    }
                }
                int w = nt * 16 + l15;
                float tvok = (w < L) ? 1.f : 0.f;
#pragma unroll
                for (int mm = 0; mm < 2; ++mm) {
#pragma unroll
                    for (int reg = 0; reg < 4; ++reg) {
                        int c = mm * 16 + quad * 4 + reg;
                        float uu = u[mm][reg];
                        float tv = (w < L) ? shB[w * 33 + c] : 0.f;
                        ss2[pp] = fmaf(uu, uu, ss2[pp]);
                        dd2[pp] = fmaf(uu, tv * tvok, dd2[pp]);
                    }
                }
            }
        }
    }
#pragma unroll
    for (int pp = 0; pp < 2; ++pp) {
        int nt = wv + 4 * pp;
        if (nt < ntot) {
            float s = ss2[pp], d = dd2[pp];
            s += __shfl_xor(s, 16, 64); d += __shfl_xor(d, 16, 64);
            s += __shfl_xor(s, 32, 64); d += __shfl_xor(d, 32, 64);
            if (quad == 0) {
                int w = nt * 16 + l15;
                if (w < L) {
                    float nu  = sqrtf(s);
                    float num = d / (nu + EPS);
                    float den = fmaxf(nVt[t * NW + w] * (nu / (nu + EPS)), EPS);
                    sCos2[w] = num / den;
                }
            }
        }
    }
    __syncthreads();
    if (tid == 0) {
        float s = 0.f;
        for (int r = 0; r < NR; ++r) s += sCos1[r];
        out[i * NT + t] = s * (1.0f / 48.0f);
    } else if (tid == 64) {
        float s = 0.f;
        for (int w = 0; w < L; ++w) s += sCos2[w];
        out[NI * NT + i * NT + t] = s / Lf;
    }
}

extern "C" void kernel_launch(void* const* d_in, const int* in_sizes, int n_in,
                              void* d_out, int out_size, void* d_ws, size_t ws_size,
                              hipStream_t stream) {
    (void)in_sizes; (void)n_in; (void)out_size;
    const float* imgQ = (const float*)d_in[0];
    const float* imgV = (const float*)d_in[1];
    const float* txtK = (const float*)d_in[2];
    const float* txtV = (const float*)d_in[3];
    const int*   tlen = (const int*)d_in[4];
    float* ws  = (float*)d_ws;
    float* out = (float*)d_out;

    hipLaunchKernelGGL(nafs_norms, dim3(6272), dim3(256), 0, stream,
                       imgQ, imgV, txtK, txtV, ws);

    if (ws_size >= WS_NEED) {
        char* base = (char*)d_ws;
        ushortt* khi = (ushortt*)(base + OFF_KHI);
        ushortt* klo = (ushortt*)(base + OFF_KLO);
        ushortt* qhi = (ushortt*)(base + OFF_QHI);
        ushortt* qlo = (ushortt*)(base + OFF_QLO);
        ushortt* tvt = (ushortt*)(base + OFF_TVT);
        ushortt* ivt = (ushortt*)(base + OFF_IVT);
        hipLaunchKernelGGL(nafs_convert, dim3(14336), dim3(256), 0, stream,
                           txtK, imgQ, ws, khi, klo, qhi, qlo);
        hipLaunchKernelGGL(nafs_ttv, dim3(1536), dim3(256), 0, stream, txtV, tvt);
        hipLaunchKernelGGL(nafs_tiv, dim3(3072), dim3(256), 0, stream, imgV, ivt);
        hipLaunchKernelGGL(nafs_fused2, dim3(NT * NI), dim3(256), 0, stream,
                           imgV, tlen, ws, khi, klo, qhi, qlo, tvt, ivt, out);
    } else {
        hipLaunchKernelGGL(nafs_fused_fb, dim3(NT * NI), dim3(256), 0, stream,
                           imgQ, imgV, txtK, txtV, tlen, ws, out);
    }
}